// Round 10
// baseline (177.112 us; speedup 1.0000x reference)
//
#include <hip/hip_runtime.h>
#include <stdint.h>

#define N_PROP 100000
#define N_LAB  256
#define NW     8                      // 256 bits / 32
#define NCHUNK 391                    // ceil(100000/256)
#define N_PAD  (NCHUNK * 256)         // 100096
#define NROWS  (NCHUNK * 4)           // 1564 rows of 64 proposals
#define NROWP  1568                   // padded stride for transposed rowOR
#define GRID   256                    // k_fused grid: 1 block/CU, all resident

// d_ws byte offsets
#define OFF_MASKS 0
#define OFF_ROWOR (N_PAD * NW * 4)                     // 3,203,072
#define OFF_KEYS  (OFF_ROWOR + NROWS * NW * 4)         // 3,253,120
#define OFF_TPCNT (OFF_KEYS + N_LAB * 8)
#define OFF_CTRL  (OFF_TPCNT + 16)
// ctrl ints: [0]=flagB [1]=ticket [2..3]=pad [4..260]=hist(257)
#define CTRL_INTS 261

__device__ __forceinline__ int ld_atomic(const int* p) {
  return __hip_atomic_load(p, __ATOMIC_RELAXED, __HIP_MEMORY_SCOPE_AGENT);
}

// first pending label from 4 x u64 pending words (-1 if none)
#define FIRST_PEND(j_i, w0, w1, w2, w3)         \
  {                                             \
    j_i = -1;                                   \
    if (w3) j_i = 192 + (__ffsll(w3) - 1);      \
    if (w2) j_i = 128 + (__ffsll(w2) - 1);      \
    if (w1) j_i = 64 + (__ffsll(w1) - 1);       \
    if (w0) j_i = (__ffsll(w0) - 1);            \
  }

// ---------------------------------------------------------------------------
// Kernel 1 (proven): per-proposal IoU>0.5 masks + per-ROW(64) ORs. Block 0
// zeroes the ctrl block (flag, ticket, hist) -- kernel boundary makes that
// visible to k_fused. Arithmetic bit-identical to the reference.
// ---------------------------------------------------------------------------
__global__ __launch_bounds__(256) void k_masks(
    const float* __restrict__ prop, const float* __restrict__ lab,
    uint32_t* __restrict__ masks, uint32_t* __restrict__ rowOR,
    int* __restrict__ ctrl) {
  __shared__ float4 s_lab[N_LAB];
  __shared__ uint32_t s_orr[4][NW];
  const int t = threadIdx.x;
  if (t < 32) s_orr[t >> 3][t & 7] = 0u;
  {
    const float bmn = lab[2 * t], bmx = lab[2 * t + 1];
    s_lab[t] = make_float4(bmn, bmx, bmx - bmn, 0.0f);
  }
  if (blockIdx.x == 0) {
    for (int z = t; z < CTRL_INTS; z += 256) ctrl[z] = 0;
  }
  __syncthreads();

  const int i = blockIdx.x * 256 + t;
  uint32_t m[NW];
#pragma unroll
  for (int w = 0; w < NW; ++w) m[w] = 0u;

  if (i < N_PROP) {
    const float ps = prop[3 * i + 1], pe = prop[3 * i + 2];
    const float amin = ps / 25.0f;
    const float amax = pe / 25.0f;
    const float alen = amax - amin;
#pragma unroll 4
    for (int j = 0; j < N_LAB; ++j) {
      const float4 L = s_lab[j];
      float inter = fminf(amax, L.y) - fmaxf(amin, L.x);
      inter = fmaxf(inter, 0.0f);
      const float uni = (alen - inter) + L.z;
      const float iou = inter / uni;           // IEEE div, as reference
      if (iou > 0.5f) m[j >> 5] |= (1u << (j & 31));
    }
  }

  uint4* mp = reinterpret_cast<uint4*>(&masks[(size_t)i * NW]);
  mp[0] = make_uint4(m[0], m[1], m[2], m[3]);
  mp[1] = make_uint4(m[4], m[5], m[6], m[7]);

  uint32_t any = 0u;
#pragma unroll
  for (int w = 0; w < NW; ++w) any |= m[w];
  if (any) {
    const int rr = t >> 6;
#pragma unroll
    for (int w = 0; w < NW; ++w)
      if (m[w]) atomicOr(&s_orr[rr][w], m[w]);
  }
  __syncthreads();
  if (t < 32) rowOR[blockIdx.x * 32 + t] = s_orr[t >> 3][t & 7];
}

// ---------------------------------------------------------------------------
// Kernel 2: fused scan+sort (block 0) / rank+AP (all 256 blocks).
// Scan claim semantics proven vs reference (absmax 0.0 R4/R6-R9): proposals
// evaluated exactly once in ascending index order; a proposal claims the
// first label of (mask & ~detected), then stops.
// R10 drain = LAZY RECOMPUTE: after a claim of label j, a lane's cached
// first-pending j_i is stale ONLY if j_i == j (D gained only bit j). The
// claimant dies; j_i==j lanes rebuild pending from their untouched mask regs
// and ~D; all others keep j_i. Claim order identical to R8/R9 (min pending
// lane each round) => exact. 8-deep static-register row pipeline (R9).
// Handoff block0 -> others is ATOMIC-ONLY (keys/tp_cnt atomic stores + flag
// spin); grid=256 = 1 block/CU => all blocks resident => spin is safe.
// ---------------------------------------------------------------------------
#define FLAGROW(RR, FV)                                                     \
  FV = (s_rT[0 * NROWP + (RR)] & ~D0) | (s_rT[1 * NROWP + (RR)] & ~D1) |    \
       (s_rT[2 * NROWP + (RR)] & ~D2) | (s_rT[3 * NROWP + (RR)] & ~D3) |    \
       (s_rT[4 * NROWP + (RR)] & ~D4) | (s_rT[5 * NROWP + (RR)] & ~D5) |    \
       (s_rT[6 * NROWP + (RR)] & ~D6) | (s_rT[7 * NROWP + (RR)] & ~D7);

#define FINDROW(RES)                                                        \
  {                                                                         \
    RES = -1;                                                               \
    while (cursor < NROWS) {                                                \
      const int rr_ = cursor + lane;                                        \
      uint32_t f_ = 0u;                                                     \
      if (rr_ < NROWS) { FLAGROW(rr_, f_); }                                \
      const unsigned long long bal_ = __ballot(f_ != 0u);                   \
      if (bal_ != 0ull) {                                                   \
        RES = cursor + (__ffsll(bal_) - 1);                                 \
        cursor = RES + 1;                                                   \
        break;                                                              \
      }                                                                     \
      cursor += 64;                                                         \
    }                                                                       \
  }

#define LOADROW(RID, MA, MB)                                                \
  {                                                                         \
    const uint4* qm_ = reinterpret_cast<const uint4*>(                      \
        &masks[(size_t)((RID) * 64 + lane) * NW]);                          \
    MA = qm_[0];                                                            \
    MB = qm_[1];                                                            \
  }

#define DRAIN64L(BASE, VA, VB)                                              \
  {                                                                         \
    const uint32_t p0 = VA.x & ~D0, p1 = VA.y & ~D1;                        \
    const uint32_t p2 = VA.z & ~D2, p3 = VA.w & ~D3;                        \
    const uint32_t p4 = VB.x & ~D4, p5 = VB.y & ~D5;                        \
    const uint32_t p6 = VB.z & ~D6, p7 = VB.w & ~D7;                        \
    unsigned long long w0 = ((unsigned long long)p1 << 32) | p0;            \
    unsigned long long w1 = ((unsigned long long)p3 << 32) | p2;            \
    unsigned long long w2 = ((unsigned long long)p5 << 32) | p4;            \
    unsigned long long w3 = ((unsigned long long)p7 << 32) | p6;            \
    int j_i;                                                                \
    FIRST_PEND(j_i, w0, w1, w2, w3);                                        \
    while (true) {                                                          \
      const unsigned long long rbal = __ballot(j_i >= 0);                   \
      if (rbal == 0ull) break;                                              \
      const int l_ = __ffsll(rbal) - 1;      /* min pending lane */         \
      const int j_ = __builtin_amdgcn_readlane(j_i, l_);                    \
      const uint32_t bit_ = 1u << (j_ & 31);                                \
      const int q5_ = j_ >> 5;                                              \
      D0 |= (q5_ == 0) ? bit_ : 0u;  D1 |= (q5_ == 1) ? bit_ : 0u;          \
      D2 |= (q5_ == 2) ? bit_ : 0u;  D3 |= (q5_ == 3) ? bit_ : 0u;          \
      D4 |= (q5_ == 4) ? bit_ : 0u;  D5 |= (q5_ == 5) ? bit_ : 0u;          \
      D6 |= (q5_ == 6) ? bit_ : 0u;  D7 |= (q5_ == 7) ? bit_ : 0u;          \
      if (lane == 0 && T < N_LAB) s_tpi[T] = (BASE) + l_;                   \
      ++T;                                                                  \
      if (lane == l_) {                                                     \
        j_i = -1;                             /* consumed: exactly once */  \
      } else if (j_i == j_) {                 /* stale: rebuild from mask */\
        const uint32_t r0_ = VA.x & ~D0, r1_ = VA.y & ~D1;                  \
        const uint32_t r2_ = VA.z & ~D2, r3_ = VA.w & ~D3;                  \
        const uint32_t r4_ = VB.x & ~D4, r5_ = VB.y & ~D5;                  \
        const uint32_t r6_ = VB.z & ~D6, r7_ = VB.w & ~D7;                  \
        w0 = ((unsigned long long)r1_ << 32) | r0_;                         \
        w1 = ((unsigned long long)r3_ << 32) | r2_;                         \
        w2 = ((unsigned long long)r5_ << 32) | r4_;                         \
        w3 = ((unsigned long long)r7_ << 32) | r6_;                         \
        FIRST_PEND(j_i, w0, w1, w2, w3);                                    \
      }                                                                     \
    }                                                                       \
  }

#define STEP(RID, MA, MB)                                                   \
  if (RID >= 0) {                                                           \
    DRAIN64L((RID) * 64, MA, MB);                                           \
    FINDROW(RID);                                                           \
    if (RID >= 0) { LOADROW(RID, MA, MB); }                                 \
  }

__global__ __launch_bounds__(256) void k_fused(
    const uint32_t* __restrict__ masks, const uint32_t* __restrict__ rowOR,
    const float* __restrict__ prop,
    unsigned long long* keys, int* tp_cnt, int* ctrl, float* out) {
  __shared__ uint32_t s_rT[NW * NROWP];        // ~50 KB (block 0 only)
  __shared__ int s_tpi[N_LAB];
  __shared__ int s_T;
  __shared__ unsigned long long s_key[N_LAB];
  __shared__ unsigned long long s_srt[N_LAB];
  __shared__ int s_hist[N_LAB + 1];
  __shared__ int s_last;
  __shared__ int s_a[N_LAB + 1];
  __shared__ int s_b[N_LAB + 1];
  __shared__ int s_p[N_LAB];
  const int t = threadIdx.x;
  const int bid = blockIdx.x;
  int* flagB = &ctrl[0];
  int* ticket = &ctrl[1];
  int* hist = &ctrl[4];

  if (bid == 0) {
    // ---- Phase B: scan + sort (reads masks/rowOR across kernel boundary) --
#pragma unroll 4
    for (int f = t; f < NROWS * NW; f += 256)
      s_rT[(f & 7) * NROWP + (f >> 3)] = rowOR[f];
    __syncthreads();

    if (t < 64) {
      const int lane = t;
      uint32_t D0 = 0, D1 = 0, D2 = 0, D3 = 0, D4 = 0, D5 = 0, D6 = 0, D7 = 0;
      int T = 0;
      int cursor = 0;
      int r0, r1, r2, r3, r4, r5, r6, r7;
      uint4 m0a = make_uint4(0,0,0,0), m0b = m0a, m1a = m0a, m1b = m0a;
      uint4 m2a = m0a, m2b = m0a, m3a = m0a, m3b = m0a;
      uint4 m4a = m0a, m4b = m0a, m5a = m0a, m5b = m0a;
      uint4 m6a = m0a, m6b = m0a, m7a = m0a, m7b = m0a;

      FINDROW(r0); if (r0 >= 0) { LOADROW(r0, m0a, m0b); }
      FINDROW(r1); if (r1 >= 0) { LOADROW(r1, m1a, m1b); }
      FINDROW(r2); if (r2 >= 0) { LOADROW(r2, m2a, m2b); }
      FINDROW(r3); if (r3 >= 0) { LOADROW(r3, m3a, m3b); }
      FINDROW(r4); if (r4 >= 0) { LOADROW(r4, m4a, m4b); }
      FINDROW(r5); if (r5 >= 0) { LOADROW(r5, m5a, m5b); }
      FINDROW(r6); if (r6 >= 0) { LOADROW(r6, m6a, m6b); }
      FINDROW(r7); if (r7 >= 0) { LOADROW(r7, m7a, m7b); }
      while (r0 >= 0 || r1 >= 0 || r2 >= 0 || r3 >= 0 ||
             r4 >= 0 || r5 >= 0 || r6 >= 0 || r7 >= 0) {
        STEP(r0, m0a, m0b);
        STEP(r1, m1a, m1b);
        STEP(r2, m2a, m2b);
        STEP(r3, m3a, m3b);
        STEP(r4, m4a, m4b);
        STEP(r5, m5a, m5b);
        STEP(r6, m6a, m6b);
        STEP(r7, m7a, m7b);
        if (T >= N_LAB) break;                 // D full: no claims possible
      }
      if (lane == 0) s_T = (T < N_LAB) ? T : N_LAB;
    }
    __syncthreads();

    // TP key build + counting sort (proven). key = conf<<32 | (~idx).
    const int T = s_T;
    unsigned long long k = ~0ull;
    if (t < T) {
      const int it = s_tpi[t];
      const unsigned cb = __float_as_uint(prop[3 * it]);
      k = ((unsigned long long)cb << 32) |
          (unsigned long long)(0xFFFFFFFFu - (unsigned)it);
    }
    s_key[t] = k;
    s_srt[t] = ~0ull;
    __syncthreads();
    int pos = 0;
    for (int s = 0; s < N_LAB; ++s) pos += (s_key[s] < k) ? 1 : 0;
    if (t < T) s_srt[pos] = k;
    __syncthreads();
    // atomic-only handoff (no cross-XCD plain-store visibility assumed)
    __hip_atomic_store(&keys[t], s_srt[t], __ATOMIC_RELAXED,
                       __HIP_MEMORY_SCOPE_AGENT);
    if (t == 0)
      __hip_atomic_store(tp_cnt, T, __ATOMIC_RELAXED,
                         __HIP_MEMORY_SCOPE_AGENT);
    __syncthreads();
    __threadfence();
    if (t == 0)
      __hip_atomic_store(flagB, 1, __ATOMIC_RELEASE,
                         __HIP_MEMORY_SCOPE_AGENT);
  } else {
    if (t == 0) {
      while (ld_atomic(flagB) == 0) __builtin_amdgcn_s_sleep(2);
    }
    __syncthreads();
    __threadfence();
  }

  // ---- Phase C: rank histogram (all blocks) + last-block AP fan-in --------
  s_key[t] = __hip_atomic_load(&keys[t], __ATOMIC_RELAXED,
                               __HIP_MEMORY_SCOPE_AGENT);
  s_hist[t] = 0;
  if (t == 0) s_hist[N_LAB] = 0;
  __syncthreads();

  for (int i = bid * 256 + t; i < N_PROP; i += GRID * 256) {
    const unsigned cb = __float_as_uint(prop[3 * i]);
    const unsigned long long k =
        ((unsigned long long)cb << 32) |
        (unsigned long long)(0xFFFFFFFFu - (unsigned)i);
    int p = 0;
#pragma unroll
    for (int s = 256; s > 0; s >>= 1) {
      const int cand = p + s;
      if (cand <= N_LAB && s_key[cand - 1] < k) p = cand;
    }
    atomicAdd(&s_hist[p], 1);
  }
  __syncthreads();
  if (s_hist[t] != 0) atomicAdd(&hist[t], s_hist[t]);
  if (t == 0 && s_hist[N_LAB] != 0) atomicAdd(&hist[N_LAB], s_hist[N_LAB]);

  __threadfence();
  if (t == 0)
    s_last = (atomicAdd(ticket, 1) == GRID - 1) ? 1 : 0;
  __syncthreads();
  if (!s_last) return;
  __threadfence();

  int T = __hip_atomic_load(tp_cnt, __ATOMIC_RELAXED,
                            __HIP_MEMORY_SCOPE_AGENT);
  T = (T < 0) ? 0 : ((T > N_LAB) ? N_LAB : T);
  s_a[t] = atomicAdd(&hist[t], 0);
  if (t == 0) s_a[N_LAB] = atomicAdd(&hist[N_LAB], 0);
  __syncthreads();
  int* src = s_a;
  int* dst = s_b;
#pragma unroll
  for (int s = 1; s <= N_LAB; s <<= 1) {        // exact int suffix scan
    const int v = src[t] + ((t + s <= N_LAB) ? src[t + s] : 0);
    const int v256 = (t == 0) ? src[N_LAB] : 0;
    __syncthreads();
    dst[t] = v;
    if (t == 0) dst[N_LAB] = v256;
    __syncthreads();
    int* tmp = src; src = dst; dst = tmp;
  }
  if (t < T) s_p[(T - 1) - t] = 1 + src[t + 1]; // ranks ascending
  __syncthreads();
  if (t == 0) {
    float m = 0.0f, sum = 0.0f;
    for (int i = T - 1; i >= 0; --i) {
      const float prec = (float)(i + 1) / (float)s_p[i];  // IEEE div, as ref
      m = fmaxf(m, prec);
      if (s_p[i] >= 2) sum += m * 0.00390625f;  // * (1/256), exact
    }
    out[0] = sum;
  }
}

extern "C" void kernel_launch(void* const* d_in, const int* in_sizes, int n_in,
                              void* d_out, int out_size, void* d_ws,
                              size_t ws_size, hipStream_t stream) {
  (void)in_sizes; (void)n_in; (void)out_size; (void)ws_size;
  const float* prop = (const float*)d_in[0];
  const float* lab  = (const float*)d_in[1];
  uint8_t* ws = (uint8_t*)d_ws;
  uint32_t* masks  = (uint32_t*)(ws + OFF_MASKS);
  uint32_t* rowOR  = (uint32_t*)(ws + OFF_ROWOR);
  unsigned long long* keys = (unsigned long long*)(ws + OFF_KEYS);
  int*      tp_cnt = (int*)(ws + OFF_TPCNT);
  int*      ctrl   = (int*)(ws + OFF_CTRL);
  float*    out    = (float*)d_out;

  k_masks<<<dim3(NCHUNK), dim3(256), 0, stream>>>(prop, lab, masks, rowOR, ctrl);
  k_fused<<<dim3(GRID),   dim3(256), 0, stream>>>(masks, rowOR, prop, keys,
                                                  tp_cnt, ctrl, out);
}

// Round 11
// 168.926 us; speedup vs baseline: 1.0485x; 1.0485x over previous
//
#include <hip/hip_runtime.h>
#include <stdint.h>

#define N_PROP 100000
#define N_LAB  256
#define NW     8                      // 256 bits / 32
#define CHUNK  256
#define NCHUNK 391                    // ceil(100000/256)
#define NCH_P  392                    // padded stride for transposed chunkOR
#define N_PAD  (NCHUNK * CHUNK)       // 100096
#define RANK_BLOCKS 128

// d_ws byte offsets
#define OFF_MASKS   0
#define OFF_CHUNKOR (N_PAD * NW * 4)                   // 3,203,072
#define OFF_KEYS    (OFF_CHUNKOR + NCHUNK * NW * 4)    // 3,215,584
#define OFF_TPCNT   (OFF_KEYS + N_LAB * 8)
#define OFF_CTRL    (OFF_TPCNT + 16)
// ctrl ints: [0]=K1 ticket, [1]=K2 ticket (both memset to 0 each call),
//            [4..260]=hist (zeroed by K1 block 0)
#define CTRL_INTS 261

// first pending label from 4 x u64 pending words (-1 if none)
#define FIRST_PEND(j_i, w0, w1, w2, w3)         \
  {                                             \
    j_i = -1;                                   \
    if (w3) j_i = 192 + (__ffsll(w3) - 1);      \
    if (w2) j_i = 128 + (__ffsll(w2) - 1);      \
    if (w1) j_i = 64 + (__ffsll(w1) - 1);       \
    if (w0) j_i = (__ffsll(w0) - 1);            \
  }

// ---- scan machinery (all pieces field-proven: R7 find/issue/revalidate,
// ---- R8 chunk structure, R10 lazy drain; absmax 0.0 in those rounds) ------
#define FLAG_LANE(CC, FVAR)                                                 \
  FVAR = (s_orT[0 * NCH_P + (CC)] & ~D0) | (s_orT[1 * NCH_P + (CC)] & ~D1) |\
         (s_orT[2 * NCH_P + (CC)] & ~D2) | (s_orT[3 * NCH_P + (CC)] & ~D3) |\
         (s_orT[4 * NCH_P + (CC)] & ~D4) | (s_orT[5 * NCH_P + (CC)] & ~D5) |\
         (s_orT[6 * NCH_P + (CC)] & ~D6) | (s_orT[7 * NCH_P + (CC)] & ~D7);

#define FIND_NEXT(C0, RES)                                                  \
  {                                                                         \
    const int start_ = (C0);            /* evaluate BEFORE touching RES */  \
    RES = -1;                                                               \
    for (int c_ = start_; c_ < NCHUNK; c_ += 64) {                          \
      const int cc_ = c_ + lane;                                            \
      uint32_t f_ = 0u;                                                     \
      if (cc_ < NCHUNK) { FLAG_LANE(cc_, f_); }                             \
      const unsigned long long bal_ = __ballot(f_ != 0u);                   \
      if (bal_ != 0ull) { RES = c_ + (__ffsll(bal_) - 1); break; }          \
    }                                                                       \
  }

// masks fully written to N_PAD rows; CH <= 390 -> max uint4 index
// 390*512+511 = 200,191 < N_PAD*NW/4 = 200,192: in-bounds.
#define ISSUE(CH, R0A, R0B, R1A, R1B, R2A, R2B, R3A, R3B)                   \
  {                                                                         \
    const uint4* qm_ =                                                      \
        reinterpret_cast<const uint4*>(&masks[(size_t)(CH) * CHUNK * NW]);  \
    const int l2_ = lane * 2;                                               \
    R0A = qm_[l2_];       R0B = qm_[l2_ + 1];                               \
    R1A = qm_[128 + l2_]; R1B = qm_[128 + l2_ + 1];                         \
    R2A = qm_[256 + l2_]; R2B = qm_[256 + l2_ + 1];                         \
    R3A = qm_[384 + l2_]; R3B = qm_[384 + l2_ + 1];                         \
  }

// Lazy-recompute drain (R10, field-proven): after claiming label j, a lane's
// cached first-pending j_i is stale ONLY if j_i == j. Claimant dies
// (evaluated exactly once); stale lanes rebuild from untouched mask regs.
// Claim order = min pending lane each round = ascending index: exact.
#define DRAIN64L(BASE, VA, VB)                                              \
  {                                                                         \
    const uint32_t p0 = VA.x & ~D0, p1 = VA.y & ~D1;                        \
    const uint32_t p2 = VA.z & ~D2, p3 = VA.w & ~D3;                        \
    const uint32_t p4 = VB.x & ~D4, p5 = VB.y & ~D5;                        \
    const uint32_t p6 = VB.z & ~D6, p7 = VB.w & ~D7;                        \
    unsigned long long w0 = ((unsigned long long)p1 << 32) | p0;            \
    unsigned long long w1 = ((unsigned long long)p3 << 32) | p2;            \
    unsigned long long w2 = ((unsigned long long)p5 << 32) | p4;            \
    unsigned long long w3 = ((unsigned long long)p7 << 32) | p6;            \
    int j_i;                                                                \
    FIRST_PEND(j_i, w0, w1, w2, w3);                                        \
    while (true) {                                                          \
      const unsigned long long rbal = __ballot(j_i >= 0);                   \
      if (rbal == 0ull) break;                                              \
      const int l_ = __ffsll(rbal) - 1;                                     \
      const int j_ = __builtin_amdgcn_readlane(j_i, l_);                    \
      const uint32_t bit_ = 1u << (j_ & 31);                                \
      const int q5_ = j_ >> 5;                                              \
      D0 |= (q5_ == 0) ? bit_ : 0u;  D1 |= (q5_ == 1) ? bit_ : 0u;          \
      D2 |= (q5_ == 2) ? bit_ : 0u;  D3 |= (q5_ == 3) ? bit_ : 0u;          \
      D4 |= (q5_ == 4) ? bit_ : 0u;  D5 |= (q5_ == 5) ? bit_ : 0u;          \
      D6 |= (q5_ == 6) ? bit_ : 0u;  D7 |= (q5_ == 7) ? bit_ : 0u;          \
      if (lane == 0 && T < N_LAB) s_tpi[T] = (BASE) + l_;                   \
      ++T;                                                                  \
      if (lane == l_) {                                                     \
        j_i = -1;                              /* consumed exactly once */  \
      } else if (j_i == j_) {                  /* stale: rebuild */         \
        const uint32_t r0_ = VA.x & ~D0, r1_ = VA.y & ~D1;                  \
        const uint32_t r2_ = VA.z & ~D2, r3_ = VA.w & ~D3;                  \
        const uint32_t r4_ = VB.x & ~D4, r5_ = VB.y & ~D5;                  \
        const uint32_t r6_ = VB.z & ~D6, r7_ = VB.w & ~D7;                  \
        w0 = ((unsigned long long)r1_ << 32) | r0_;                         \
        w1 = ((unsigned long long)r3_ << 32) | r2_;                         \
        w2 = ((unsigned long long)r5_ << 32) | r4_;                         \
        w3 = ((unsigned long long)r7_ << 32) | r6_;                         \
        FIRST_PEND(j_i, w0, w1, w2, w3);                                    \
      }                                                                     \
    }                                                                       \
  }

#define COPY_BA                                                             \
  a0A = b0A; a0B = b0B; a1A = b1A; a1B = b1B;                               \
  a2A = b2A; a2B = b2B; a3A = b3A; a3B = b3B;

// ---------------------------------------------------------------------------
// Kernel 1: masks (all 391 blocks, bit-exact vs reference) + last-arriving
// block runs scan+sort. Ticket fan-in, NO spinning: losers exit.
// Release: each block __threadfence() after its mask/chunkOR writes, then
// ticket atomicAdd. Winner (sees 390): __threadfence() acquire -> all other
// blocks' writes are complete and fresh. Scan claim semantics proven
// (absmax 0.0, R4/R6-R10).
// ---------------------------------------------------------------------------
__global__ __launch_bounds__(256) void k_masks_scan(
    const float* __restrict__ prop, const float* __restrict__ lab,
    uint32_t* __restrict__ masks, uint32_t* __restrict__ chunkOR,
    int* ctrl, unsigned long long* keys, int* tp_cnt) {
  __shared__ float4 s_lab[N_LAB];
  __shared__ uint32_t s_or[NW];
  __shared__ uint32_t s_orT[NW * NCH_P];       // 12.5 KB (scan phase)
  __shared__ int s_tpi[N_LAB];
  __shared__ int s_T;
  __shared__ int s_last;
  __shared__ unsigned long long s_key[N_LAB];
  __shared__ unsigned long long s_srt[N_LAB];
  const int t = threadIdx.x;

  // ---- masks phase (bit-identical arithmetic, proven) ----
  if (t < NW) s_or[t] = 0u;
  {
    const float bmn = lab[2 * t], bmx = lab[2 * t + 1];
    s_lab[t] = make_float4(bmn, bmx, bmx - bmn, 0.0f);
  }
  if (blockIdx.x == 0) {
    for (int z = 4 + t; z < CTRL_INTS; z += 256) ctrl[z] = 0;  // hist
  }
  __syncthreads();

  const int i = blockIdx.x * 256 + t;
  uint32_t m[NW];
#pragma unroll
  for (int w = 0; w < NW; ++w) m[w] = 0u;

  if (i < N_PROP) {
    const float ps = prop[3 * i + 1], pe = prop[3 * i + 2];
    const float amin = ps / 25.0f;
    const float amax = pe / 25.0f;
    const float alen = amax - amin;
#pragma unroll 4
    for (int j = 0; j < N_LAB; ++j) {
      const float4 L = s_lab[j];
      float inter = fminf(amax, L.y) - fmaxf(amin, L.x);
      inter = fmaxf(inter, 0.0f);
      const float uni = (alen - inter) + L.z;
      const float iou = inter / uni;           // IEEE div, as reference
      if (iou > 0.5f) m[j >> 5] |= (1u << (j & 31));
    }
  }

  uint4* mp = reinterpret_cast<uint4*>(&masks[(size_t)i * NW]);
  mp[0] = make_uint4(m[0], m[1], m[2], m[3]);
  mp[1] = make_uint4(m[4], m[5], m[6], m[7]);

  uint32_t any = 0u;
#pragma unroll
  for (int w = 0; w < NW; ++w) any |= m[w];
  if (any) {
#pragma unroll
    for (int w = 0; w < NW; ++w)
      if (m[w]) atomicOr(&s_or[w], m[w]);
  }
  __syncthreads();
  if (t < NW) chunkOR[blockIdx.x * NW + t] = s_or[t];

  // ---- ticket: last-arriving block proceeds to scan ----
  __threadfence();                              // release this block's writes
  __syncthreads();                              // all threads' stores issued
  if (t == 0)
    s_last = (atomicAdd(&ctrl[0], 1) == NCHUNK - 1) ? 1 : 0;
  __syncthreads();
  if (!s_last) return;
  __threadfence();                              // acquire all blocks' writes

  // ---- scan phase (wave 0 of the winner) ----
  for (int f = t; f < NCHUNK * NW; f += 256)
    s_orT[(f & 7) * NCH_P + (f >> 3)] = chunkOR[f];
  __syncthreads();

  if (t < 64) {
    const int lane = t;
    uint32_t D0 = 0, D1 = 0, D2 = 0, D3 = 0, D4 = 0, D5 = 0, D6 = 0, D7 = 0;
    int T = 0;
    uint4 a0A, a0B, a1A, a1B, a2A, a2B, a3A, a3B;
    uint4 b0A, b0B, b1A, b1B, b2A, b2B, b3A, b3B;

    int cur;
    FIND_NEXT(0, cur);
    if (cur >= 0) { ISSUE(cur, a0A, a0B, a1A, a1B, a2A, a2B, a3A, a3B); }
    while (cur >= 0) {
      int nxt;
      FIND_NEXT(cur + 1, nxt);                 // superset test (pre-drain D)
      if (nxt >= 0) { ISSUE(nxt, b0A, b0B, b1A, b1B, b2A, b2B, b3A, b3B); }

      DRAIN64L(cur * CHUNK + 0,   a0A, a0B);
      DRAIN64L(cur * CHUNK + 64,  a1A, a1B);
      DRAIN64L(cur * CHUNK + 128, a2A, a2B);
      DRAIN64L(cur * CHUNK + 192, a3A, a3B);

      if (T >= N_LAB) break;                   // detected full
      while (nxt >= 0) {                       // re-validate under grown D
        uint32_t fu;
        FLAG_LANE(nxt, fu);
        if (fu != 0u) break;
        FIND_NEXT(nxt + 1, nxt);
        if (nxt >= 0) { ISSUE(nxt, b0A, b0B, b1A, b1B, b2A, b2B, b3A, b3B); }
      }
      cur = nxt;                               // strictly increases
      if (cur >= 0) { COPY_BA }
    }
    if (lane == 0) s_T = (T < N_LAB) ? T : N_LAB;
  }
  __syncthreads();

  // ---- sort phase (all 256 threads; proven) ----
  const int T = s_T;
  unsigned long long k = ~0ull;
  if (t < T) {
    const int it = s_tpi[t];
    const unsigned cb = __float_as_uint(prop[3 * it]);
    k = ((unsigned long long)cb << 32) |
        (unsigned long long)(0xFFFFFFFFu - (unsigned)it);
  }
  s_key[t] = k;
  s_srt[t] = ~0ull;
  __syncthreads();
  int pos = 0;
  for (int s = 0; s < N_LAB; ++s) pos += (s_key[s] < k) ? 1 : 0;
  if (t < T) s_srt[pos] = k;                   // real keys distinct
  __syncthreads();
  keys[t] = s_srt[t];                          // kernel boundary -> K2
  if (t == 0) tp_cnt[0] = T;
}

// ---------------------------------------------------------------------------
// Kernel 2 (R9, proven): rank histogram (128 blocks) + last-block AP fan-in.
// p_i = #{sorted TP keys < key_i} (exact 9-step lower_bound). AP computed by
// the ticket winner: exact int suffix-scan + bit-exact fp loop.
// AP = (1/256) * sum_{i: p_i >= 2} max_{j>=i} (j / p_j); rank-1 excluded.
// ---------------------------------------------------------------------------
__global__ __launch_bounds__(256) void k_rankap(
    const float* __restrict__ prop, const unsigned long long* __restrict__ keys,
    const int* __restrict__ tp_cnt, int* ctrl, float* __restrict__ out) {
  __shared__ unsigned long long s_key[N_LAB];
  __shared__ int s_hist[N_LAB + 1];
  __shared__ int s_last;
  __shared__ int s_a[N_LAB + 1];
  __shared__ int s_b[N_LAB + 1];
  __shared__ int s_p[N_LAB];
  const int t = threadIdx.x;
  int* hist = &ctrl[4];
  s_key[t] = keys[t];
  s_hist[t] = 0;
  if (t == 0) s_hist[N_LAB] = 0;
  __syncthreads();

  for (int i = blockIdx.x * 256 + t; i < N_PROP; i += RANK_BLOCKS * 256) {
    const unsigned cb = __float_as_uint(prop[3 * i]);
    const unsigned long long k =
        ((unsigned long long)cb << 32) |
        (unsigned long long)(0xFFFFFFFFu - (unsigned)i);
    int p = 0;
#pragma unroll
    for (int s = 256; s > 0; s >>= 1) {
      const int cand = p + s;
      if (cand <= N_LAB && s_key[cand - 1] < k) p = cand;
    }
    atomicAdd(&s_hist[p], 1);
  }
  __syncthreads();
  if (s_hist[t] != 0) atomicAdd(&hist[t], s_hist[t]);
  if (t == 0 && s_hist[N_LAB] != 0) atomicAdd(&hist[N_LAB], s_hist[N_LAB]);

  __threadfence();                              // release partials
  if (t == 0)
    s_last = (atomicAdd(&ctrl[1], 1) == RANK_BLOCKS - 1) ? 1 : 0;
  __syncthreads();
  if (!s_last) return;
  __threadfence();                              // acquire partials

  int T = tp_cnt[0];
  T = (T < 0) ? 0 : ((T > N_LAB) ? N_LAB : T);
  s_a[t] = atomicAdd(&hist[t], 0);              // coherent read
  if (t == 0) s_a[N_LAB] = atomicAdd(&hist[N_LAB], 0);
  __syncthreads();
  int* src = s_a;
  int* dst = s_b;
#pragma unroll
  for (int s = 1; s <= N_LAB; s <<= 1) {        // exact int suffix scan
    const int v = src[t] + ((t + s <= N_LAB) ? src[t + s] : 0);
    const int v256 = (t == 0) ? src[N_LAB] : 0;
    __syncthreads();
    dst[t] = v;
    if (t == 0) dst[N_LAB] = v256;
    __syncthreads();
    int* tmp = src; src = dst; dst = tmp;
  }
  if (t < T) s_p[(T - 1) - t] = 1 + src[t + 1]; // ranks ascending
  __syncthreads();
  if (t == 0) {
    float m = 0.0f, sum = 0.0f;
    for (int i = T - 1; i >= 0; --i) {
      const float prec = (float)(i + 1) / (float)s_p[i];  // IEEE div, as ref
      m = fmaxf(m, prec);
      if (s_p[i] >= 2) sum += m * 0.00390625f;  // * (1/256), exact
    }
    out[0] = sum;
  }
}

extern "C" void kernel_launch(void* const* d_in, const int* in_sizes, int n_in,
                              void* d_out, int out_size, void* d_ws,
                              size_t ws_size, hipStream_t stream) {
  (void)in_sizes; (void)n_in; (void)out_size; (void)ws_size;
  const float* prop = (const float*)d_in[0];
  const float* lab  = (const float*)d_in[1];
  uint8_t* ws = (uint8_t*)d_ws;
  uint32_t* masks  = (uint32_t*)(ws + OFF_MASKS);
  uint32_t* chOR   = (uint32_t*)(ws + OFF_CHUNKOR);
  unsigned long long* keys = (unsigned long long*)(ws + OFF_KEYS);
  int*      tp_cnt = (int*)(ws + OFF_TPCNT);
  int*      ctrl   = (int*)(ws + OFF_CTRL);
  float*    out    = (float*)d_out;

  // zero the two tickets each call (graph-capture-safe async memset)
  hipMemsetAsync(ctrl, 0, 8, stream);
  k_masks_scan<<<dim3(NCHUNK),      dim3(256), 0, stream>>>(
      prop, lab, masks, chOR, ctrl, keys, tp_cnt);
  k_rankap    <<<dim3(RANK_BLOCKS), dim3(256), 0, stream>>>(
      prop, keys, tp_cnt, ctrl, out);
}